// Round 7
// baseline (16.054 us; speedup 1.0000x reference)
//
#include <hip/hip_runtime.h>
#include <math.h>

#define HEADS 8
#define BATCH 4
#define SEQ 2048
#define CDIM 32
#define WINDOW 10
#define WSZ 21                       // keys per query row
#define RPB 64                       // query rows per block
#define BAND (RPB + 2 * WINDOW)      // 84 band rows (K staged in LDS)
#define KCHUNKS 11                   // ceil(BAND*8 / 64) gload_lds wave-chunks

// DPP cross-lane add (pure VALU). xor1 = quad_perm 0xB1, xor2 = quad_perm
// 0x4E, cross-quad within 8-lane group = row_half_mirror 0x141.
#define DPP_ADD(x, ctrl) \
    ((x) + __int_as_float(__builtin_amdgcn_mov_dpp(__float_as_int(x), (ctrl), 0xF, 0xF, true)))

// R6 design: K band in LDS (DS pipe, ds_read_b128), V band via global/L1
// (TA pipe), 2 query rows per 8-lane group (each K/V fetch feeds 2 rows).
// DS bytes per row drop 4x vs R5; V stream moves to an independent pipe.
__global__ __launch_bounds__(256) void lwin_attn_kernel(
    const float* __restrict__ Q, const float* __restrict__ K,
    const float* __restrict__ V, const float* __restrict__ G,
    const unsigned char* __restrict__ seqMask, float* __restrict__ out)
{
    __shared__ float k_lds[KCHUNKS * 256];   // 11264 B, rows 84..87 are pad
    __shared__ unsigned long long bm_lds[2]; // band invalid mask, bits 0..83

    // XCD-aware swizzle: XCD (d%8) owns a contiguous 128-block chunk
    // (= 4 full (h,n) panels); adjacent bands overlap 20/64 rows -> L2 hits.
    const int d = blockIdx.x;
    const int b = (d & 7) * 128 + (d >> 3);

    const int hn = b >> 5;                       // h*BATCH + n (32 blocks per hn)
    const int s0 = (b & 31) * RPB;
    const int n  = hn & 3;
    const int h  = hn >> 2;
    const int base_hn = hn * SEQ * CDIM;

    const int wv   = threadIdx.x >> 6;
    const int lane = threadIdx.x & 63;
    const int gl   = threadIdx.x >> 3;           // group 0..31
    const int sub  = threadIdx.x & 7;
    const int c0   = sub * 4;
    const int ra   = gl * 2;                     // local row a (even), 0..62
    const int sa   = s0 + ra;
    const int rowa = hn * SEQ + sa;

    // ---- prefetch Q, G early (overlaps staging latency) ----
    float4 qa = *(const float4*)&Q[rowa * CDIM + c0];
    float4 qb = *(const float4*)&Q[(rowa + 1) * CDIM + c0];
    const float4 ga = *(const float4*)&G[rowa * CDIM + c0];
    const float4 gb = *(const float4*)&G[(rowa + 1) * CDIM + c0];

    // ---- band invalid mask: 2 ballots (rows 0..63, 64..83) ----
    if (wv < 2) {
        const int i  = wv * 64 + lane;           // 0..127 (bits >=84 unused)
        const int t  = s0 - WINDOW + i;
        const int tc = min(max(t, 0), SEQ - 1);
        const bool invalid = (t < 0) || (t >= SEQ) || (seqMask[n * SEQ + tc] != 0);
        const unsigned long long bmw = __ballot(invalid);
        if (lane == 0) bm_lds[wv] = bmw;
    }

    // ---- stage K band via async global->LDS (11 wave-chunks of 64x16B) ----
#if defined(__has_builtin) && __has_builtin(__builtin_amdgcn_global_load_lds)
    for (int t = wv; t < KCHUNKS; t += 4) {
        const int task = t * 64 + lane;
        const int i    = min(task >> 3, BAND - 1);
        const int ch   = (task & 7) * 4;
        const int tr   = s0 - WINDOW + i;
        const int tc   = min(max(tr, 0), SEQ - 1);
        const float* src = K + base_hn + tc * CDIM + ch;
        __builtin_amdgcn_global_load_lds(
            (const __attribute__((address_space(1))) void*)src,
            (__attribute__((address_space(3))) void*)(k_lds + t * 256),
            16, 0, 0);
    }
#else
    for (int it = 0; it < 3; ++it) {
        const int task = threadIdx.x + it * 256;
        if (task < BAND * 8) {
            const int i  = task >> 3;
            const int ch = (task & 7) * 4;
            const int tr = s0 - WINDOW + i;
            const int tc = min(max(tr, 0), SEQ - 1);
            *(float4*)&k_lds[task * 4] = *(const float4*)&K[base_hn + tc * CDIM + ch];
        }
    }
#endif
    __syncthreads();

    // log2-domain softmax: fold 1/sqrt(32)*log2(e) into the Q scale.
    const float scale = 0.17677669529663687f * 1.4426950408889634f;
    qa.x *= scale; qa.y *= scale; qa.z *= scale; qa.w *= scale;
    qb.x *= scale; qb.y *= scale; qb.z *= scale; qb.w *= scale;

    // 21-bit invalid windows for rows a,b extracted from the 84-bit mask.
    // ((bm1 << (63-p)) << 1) == bm1 << (64-p), and is exactly 0 when p==0.
    const unsigned long long bm0 = bm_lds[0];
    const unsigned long long bm1 = bm_lds[1];
    const unsigned long long mm =
        (bm0 >> ra) | ((bm1 << (63 - ra)) << 1);
    const unsigned int bmA = (unsigned int)mm;          // bits 0..20
    const unsigned int bmB = (unsigned int)(mm >> 1);   // bits 0..20

    // ---- QK^T from LDS: 22 K rows cover both query rows ----
    float sA[WSZ], sB[WSZ];
#pragma unroll
    for (int m = 0; m <= WSZ; ++m) {
        const float4 k = *(const float4*)&k_lds[(ra + m) * CDIM + c0];
        if (m < WSZ) {
            float pa = fmaf(qa.x, k.x, fmaf(qa.y, k.y, fmaf(qa.z, k.z, qa.w * k.w)));
            pa = DPP_ADD(pa, 0xB1);
            pa = DPP_ADD(pa, 0x4E);
            pa = DPP_ADD(pa, 0x141);
            sA[m] = ((bmA >> m) & 1u) ? -1e30f : pa;
        }
        if (m >= 1) {
            float pb = fmaf(qb.x, k.x, fmaf(qb.y, k.y, fmaf(qb.z, k.z, qb.w * k.w)));
            pb = DPP_ADD(pb, 0xB1);
            pb = DPP_ADD(pb, 0x4E);
            pb = DPP_ADD(pb, 0x141);
            sB[m - 1] = ((bmB >> (m - 1)) & 1u) ? -1e30f : pb;
        }
    }

    // ---- softmax (log2 domain) ----
    float mA = -1e30f, mB = -1e30f;
#pragma unroll
    for (int j = 0; j < WSZ; ++j) { mA = fmaxf(mA, sA[j]); mB = fmaxf(mB, sB[j]); }
    float sumA = 0.f, sumB = 0.f;
#pragma unroll
    for (int j = 0; j < WSZ; ++j) {
        const float ea = __builtin_amdgcn_exp2f(sA[j] - mA);
        const float eb = __builtin_amdgcn_exp2f(sB[j] - mB);
        sA[j] = ea; sB[j] = eb;
        sumA += ea; sumB += eb;
    }
    const float invA = 1.0f / sumA;
    const float invB = 1.0f / sumB;

    // ---- PV from GLOBAL (L1/L2-resident band; swizzle keeps it local) ----
    const float* __restrict__ vbase = V + base_hn + c0;
    float4 accA = make_float4(0.f, 0.f, 0.f, 0.f);
    float4 accB = make_float4(0.f, 0.f, 0.f, 0.f);
#pragma unroll
    for (int m = 0; m <= WSZ; ++m) {
        const int t  = sa - WINDOW + m;
        const int tc = min(max(t, 0), SEQ - 1);
        const float4 v = *(const float4*)&vbase[tc * CDIM];
        if (m < WSZ) {
            accA.x = fmaf(sA[m], v.x, accA.x);
            accA.y = fmaf(sA[m], v.y, accA.y);
            accA.z = fmaf(sA[m], v.z, accA.z);
            accA.w = fmaf(sA[m], v.w, accA.w);
        }
        if (m >= 1) {
            accB.x = fmaf(sB[m - 1], v.x, accB.x);
            accB.y = fmaf(sB[m - 1], v.y, accB.y);
            accB.z = fmaf(sB[m - 1], v.z, accB.z);
            accB.w = fmaf(sB[m - 1], v.w, accB.w);
        }
    }

    float4 oa, ob;
    oa.x = accA.x * invA * ga.x;  oa.y = accA.y * invA * ga.y;
    oa.z = accA.z * invA * ga.z;  oa.w = accA.w * invA * ga.w;
    ob.x = accB.x * invB * gb.x;  ob.y = accB.y * invB * gb.y;
    ob.z = accB.z * invB * gb.z;  ob.w = accB.w * invB * gb.w;

    // out[n, s, h, i]
    *(float4*)&out[((n * SEQ + sa) * HEADS + h) * CDIM + c0] = oa;
    *(float4*)&out[((n * SEQ + sa + 1) * HEADS + h) * CDIM + c0] = ob;
}

extern "C" void kernel_launch(void* const* d_in, const int* in_sizes, int n_in,
                              void* d_out, int out_size, void* d_ws, size_t ws_size,
                              hipStream_t stream) {
    const float* Q = (const float*)d_in[0];
    const float* K = (const float*)d_in[1];
    const float* V = (const float*)d_in[2];
    const float* G = (const float*)d_in[3];
    const unsigned char* seqMask = (const unsigned char*)d_in[4];
    float* out = (float*)d_out;

    const int blocks = HEADS * BATCH * (SEQ / RPB);   // 1024
    lwin_attn_kernel<<<blocks, 256, 0, stream>>>(Q, K, V, G, seqMask, out);
}

// Round 9
// 12.581 us; speedup vs baseline: 1.2760x; 1.2760x over previous
//
#include <hip/hip_runtime.h>
#include <hip/hip_bf16.h>
#include <math.h>

#define HEADS 8
#define BATCH 4
#define SEQ 2048
#define CDIM 32
#define WINDOW 10

#define RPB 64                 // rows per block = 4 waves x 16-row MFMA tiles
#define KROWS 96               // K band rows staged: s0-16 .. s0+79
#define VROWS 112              // V rows padded so PV reads (max row 111) stay in-bounds

typedef float f32x4 __attribute__((ext_vector_type(4)));
typedef short s16x8 __attribute__((ext_vector_type(8)));
#define MFMA16 __builtin_amdgcn_mfma_f32_16x16x32_bf16

union BF8 { s16x8 v; __hip_bfloat162 h[4]; };
union U32 { __hip_bfloat162 h; unsigned u; };
union U4  { unsigned u[4]; s16x8 v; };
union US  { unsigned short s[8]; s16x8 v; };

// Per-wave 16-row tile. Slot space: 48 key slots per tile, slot j <-> key
// t = sw - 16 + j (sw = tile first row). Band-valid iff |j - 16 - q| <= 10.
// QK^T: C[key][query] via mfma(A=K, B=Q): col=lane&15=query, row=(lane>>4)*4+reg=key.
__global__ __launch_bounds__(256) void lwin_attn_kernel(
    const float* __restrict__ Q, const float* __restrict__ K,
    const float* __restrict__ V, const float* __restrict__ G,
    const unsigned char* __restrict__ seqMask, float* __restrict__ out)
{
    __shared__ short K_s[KROWS * 32];           // bf16 K band, row-major [96][32]
    __shared__ short V_s[VROWS * 32];           // bf16 V band, row-major [112][32]
    __shared__ unsigned long long bm_lds[2];    // 96-bit band invalid mask

    // XCD-aware swizzle (1024 blocks, 128 per XCD chunk)
    const int d = blockIdx.x;
    const int b = (d & 7) * 128 + (d >> 3);

    const int hn = b >> 5;                      // h*BATCH + n (32 blocks per hn)
    const int s0 = (b & 31) * RPB;
    const int n  = hn & 3;
    const int h  = hn >> 2;
    const int base_hn = hn * SEQ * CDIM;

    const int tid  = threadIdx.x;
    const int w    = tid >> 6;                  // wave = tile index 0..3
    const int lane = tid & 63;
    const int q    = lane & 15;                 // query-in-tile / MFMA col
    const int g    = lane >> 4;                 // lane group

    // ---- band invalid mask: rows i=0..95 <-> key t = s0-16+i ----
    if (w < 2) {
        const int i  = w * 64 + lane;
        const int t  = s0 - 16 + i;
        const int tc = min(max(t, 0), SEQ - 1);
        const bool inval = (t < 0) || (t >= SEQ) || (seqMask[n * SEQ + tc] != 0);
        const unsigned long long bw = __ballot(inval);
        if (lane == 0) bm_lds[w] = bw;
    }

    // ---- stage K (384 tasks) and V (448 tasks) as bf16, row-major ----
#pragma unroll
    for (int it = 0; it < 4; ++it) {
        const int task = tid + it * 256;
        if (task < 384) {                       // K: i = 0..95, octet o = 0..3
            const int i = task >> 2, o = task & 3;
            const int t  = s0 - 16 + i;
            const int tc = min(max(t, 0), SEQ - 1);
            const float4 f0 = *(const float4*)&K[base_hn + tc * 32 + 8 * o];
            const float4 f1 = *(const float4*)&K[base_hn + tc * 32 + 8 * o + 4];
            BF8 u;
            u.h[0] = __float22bfloat162_rn(make_float2(f0.x, f0.y));
            u.h[1] = __float22bfloat162_rn(make_float2(f0.z, f0.w));
            u.h[2] = __float22bfloat162_rn(make_float2(f1.x, f1.y));
            u.h[3] = __float22bfloat162_rn(make_float2(f1.z, f1.w));
            *(s16x8*)&K_s[i * 32 + 8 * o] = u.v;
        } else if (task < 384 + 448) {          // V: i = 0..111 (padded rows clamp)
            const int vt = task - 384;
            const int i = vt >> 2, o = vt & 3;
            const int t  = s0 - 16 + i;
            const int tc = min(max(t, 0), SEQ - 1);
            const float4 f0 = *(const float4*)&V[base_hn + tc * 32 + 8 * o];
            const float4 f1 = *(const float4*)&V[base_hn + tc * 32 + 8 * o + 4];
            BF8 u;
            u.h[0] = __float22bfloat162_rn(make_float2(f0.x, f0.y));
            u.h[1] = __float22bfloat162_rn(make_float2(f0.z, f0.w));
            u.h[2] = __float22bfloat162_rn(make_float2(f1.x, f1.y));
            u.h[3] = __float22bfloat162_rn(make_float2(f1.z, f1.w));
            *(s16x8*)&V_s[i * 32 + 8 * o] = u.v;
        }
    }

    // ---- Q B-fragment: lane holds Q[sw+q][ch 8g..8g+7], scaled, bf16 ----
    const int sw   = s0 + 16 * w;
    const int rowq = hn * SEQ + sw + q;
    const float sc = 0.17677669529663687f * 1.4426950408889634f; // 1/sqrt(32)*log2e
    const float4 q0 = *(const float4*)&Q[rowq * 32 + 8 * g];
    const float4 q1 = *(const float4*)&Q[rowq * 32 + 8 * g + 4];
    BF8 bq;
    bq.h[0] = __float22bfloat162_rn(make_float2(q0.x * sc, q0.y * sc));
    bq.h[1] = __float22bfloat162_rn(make_float2(q0.z * sc, q0.w * sc));
    bq.h[2] = __float22bfloat162_rn(make_float2(q1.x * sc, q1.y * sc));
    bq.h[3] = __float22bfloat162_rn(make_float2(q1.z * sc, q1.w * sc));

    __syncthreads();

    // ---- QK^T: 3 MFMAs over key blocks; S[blk][r] = S[key=16blk+4g+r][q] ----
    f32x4 S[3];
#pragma unroll
    for (int blk = 0; blk < 3; ++blk) {
        const s16x8 ak = *(const s16x8*)&K_s[(16 * w + 16 * blk + q) * 32 + 8 * g];
        S[blk] = MFMA16(ak, bq.v, (f32x4){0.f, 0.f, 0.f, 0.f}, 0, 0, 0);
    }

    // ---- mask + softmax (scores for query q live in lanes q, q+16, q+32, q+48) ----
    const unsigned long long bm0 = bm_lds[0], bm1 = bm_lds[1];
    bool vld[3][4];
    float mx = -1e30f;
#pragma unroll
    for (int blk = 0; blk < 3; ++blk)
#pragma unroll
        for (int r = 0; r < 4; ++r) {
            const int j = 16 * blk + 4 * g + r;       // slot 0..47
            const int i = 16 * w + j;                 // band row 0..95
            const int rel = j - 16 - q;               // key - query offset
            const bool band_ok = (rel >= -WINDOW) && (rel <= WINDOW);
            const bool bm_ok =
                !(((i < 64) ? (bm0 >> i) : (bm1 >> (i - 64))) & 1ULL);
            vld[blk][r] = band_ok && bm_ok;
            mx = fmaxf(mx, vld[blk][r] ? S[blk][r] : -1e30f);
        }
    mx = fmaxf(mx, __shfl_xor(mx, 16));
    mx = fmaxf(mx, __shfl_xor(mx, 32));

    float P[3][4];
    float sm = 0.f;
#pragma unroll
    for (int blk = 0; blk < 3; ++blk)
#pragma unroll
        for (int r = 0; r < 4; ++r) {
            const float e = vld[blk][r] ? __builtin_amdgcn_exp2f(S[blk][r] - mx) : 0.f;
            P[blk][r] = e;
            sm += e;
        }
    sm += __shfl_xor(sm, 16);
    sm += __shfl_xor(sm, 32);
    const float inv = 1.0f / sm;

    // ---- pack P (with inv folded) to bf16 pairs: pk[blk][par] ----
    unsigned pk[3][2];
#pragma unroll
    for (int blk = 0; blk < 3; ++blk) {
        U32 a, b2;
        a.h  = __float22bfloat162_rn(make_float2(P[blk][0] * inv, P[blk][1] * inv));
        b2.h = __float22bfloat162_rn(make_float2(P[blk][2] * inv, P[blk][3] * inv));
        pk[blk][0] = a.u;
        pk[blk][1] = b2.u;
    }

    // ---- relayout P into A-fragments (lane q needs slots 8g..8g+7 / 32+8g..) ----
    // pair j: source lane = q + 16*(2*(g&1) + (j>>1)), source reg pk[blk][j&1];
    // A1 blk = g>>1, A2 blk = 2 (slots 32..47, zero-padded for g>=2).
    U4 A1, A2;
#pragma unroll
    for (int j = 0; j < 4; ++j) {
        const int srcl = q + 16 * (2 * (g & 1) + (j >> 1));
        const unsigned x0 = __shfl(pk[0][j & 1], srcl);
        const unsigned x1 = __shfl(pk[1][j & 1], srcl);
        const unsigned x2 = __shfl(pk[2][j & 1], srcl);
        A1.u[j] = (g >> 1) ? x1 : x0;
        A2.u[j] = (g < 2) ? x2 : 0u;
    }

    // ---- PV: B-fragments built from scalar LDS column reads (verified
    // semantics; replaces the suspect ds_read_b64_tr_b16 of R7).
    // Lane (q,g) needs B[k=8g+j][col] = V[row 16w+32sb+8g+j][ch col]. ----
    f32x4 O0 = {0.f, 0.f, 0.f, 0.f}, O1 = {0.f, 0.f, 0.f, 0.f};
    const unsigned short* __restrict__ vs = (const unsigned short*)V_s;
#pragma unroll
    for (int sb = 0; sb < 2; ++sb) {
        US b0, b1;
#pragma unroll
        for (int j = 0; j < 8; ++j) {
            const int vrow = 16 * w + 32 * sb + 8 * g + j;   // <= 111
            b0.s[j] = vs[vrow * 32 + q];
            b1.s[j] = vs[vrow * 32 + q + 16];
        }
        const s16x8 Af = (sb == 0) ? A1.v : A2.v;
        O0 = MFMA16(Af, b0.v, O0, 0, 0, 0);
        O1 = MFMA16(Af, b1.v, O1, 0, 0, 0);
    }

    // ---- epilogue: O[row=4g+r][ch=q+16p] * G, store to out[n,s,h,ch] ----
#pragma unroll
    for (int p = 0; p < 2; ++p)
#pragma unroll
        for (int r = 0; r < 4; ++r) {
            const int orow = sw + 4 * g + r;
            const int ch   = q + 16 * p;
            const float gv = G[(hn * SEQ + orow) * 32 + ch];
            const float ov = (p == 0) ? O0[r] : O1[r];
            out[((n * SEQ + orow) * HEADS + h) * 32 + ch] = ov * gv;
        }
}

extern "C" void kernel_launch(void* const* d_in, const int* in_sizes, int n_in,
                              void* d_out, int out_size, void* d_ws, size_t ws_size,
                              hipStream_t stream) {
    const float* Q = (const float*)d_in[0];
    const float* K = (const float*)d_in[1];
    const float* V = (const float*)d_in[2];
    const float* G = (const float*)d_in[3];
    const unsigned char* seqMask = (const unsigned char*)d_in[4];
    float* out = (float*)d_out;

    const int blocks = HEADS * BATCH * (SEQ / RPB);   // 1024
    lwin_attn_kernel<<<blocks, 256, 0, stream>>>(Q, K, V, G, seqMask, out);
}

// Round 10
// 11.955 us; speedup vs baseline: 1.3428x; 1.0524x over previous
//
#include <hip/hip_runtime.h>
#include <hip/hip_bf16.h>
#include <math.h>

#define HEADS 8
#define BATCH 4
#define SEQ 2048
#define CDIM 32
#define WINDOW 10

#define RPB 64                 // rows per block = 4 waves x 16-row MFMA tiles
#define KROWS 96               // K band rows staged: s0-16 .. s0+79
#define VROWS 112              // V rows padded so PV reads (max row 111) stay in-bounds
#define VSTR 20                // u32 stride of packed V rows (16 + 4 pad: 2-way banks)

typedef float f32x4 __attribute__((ext_vector_type(4)));
typedef short s16x8 __attribute__((ext_vector_type(8)));
#define MFMA16 __builtin_amdgcn_mfma_f32_16x16x32_bf16

union BF8 { s16x8 v; __hip_bfloat162 h[4]; };
union U32 { __hip_bfloat162 h; unsigned u; };
union U4  { unsigned u[4]; s16x8 v; };

// Per-wave 16-row tile; 48 key slots j <-> key t = sw-16+j; valid iff
// j in [q+6, q+26] and not seq-masked.
// QK^T: C[key][query] = mfma(A=K, B=Q)  -> lane(q,g) reg r: key 16blk+4g+r.
// PV (operand-swapped): O^T[ch][query] = mfma(A=Vfrag, B=Pfrag) with shared
// slot->key bijection f(g,j) = 4g+j (j<4) / 16+4g+(j-4) (j>=4) -> P needs NO
// cross-lane relayout (pk words are already in the right lane).
__global__ __launch_bounds__(256) void lwin_attn_kernel(
    const float* __restrict__ Q, const float* __restrict__ K,
    const float* __restrict__ V, const float* __restrict__ G,
    const unsigned char* __restrict__ seqMask, float* __restrict__ out)
{
    __shared__ short K_s[KROWS * 32];           // bf16 K band, row-major [96][32]
    __shared__ unsigned V_s[VROWS * VSTR];      // packed (ch c, ch c+16) bf16 pairs
    __shared__ unsigned long long bm_lds[2];    // 96-bit band invalid mask

    // XCD-aware swizzle (1024 blocks, 128 per XCD chunk)
    const int d = blockIdx.x;
    const int b = (d & 7) * 128 + (d >> 3);

    const int hn = b >> 5;                      // h*BATCH + n (32 blocks per hn)
    const int s0 = (b & 31) * RPB;
    const int n  = hn & 3;
    const int h  = hn >> 2;
    const int base_hn = hn * SEQ * CDIM;

    const int tid  = threadIdx.x;
    const int w    = tid >> 6;                  // wave = tile index 0..3
    const int lane = tid & 63;
    const int q    = lane & 15;                 // query-in-tile / MFMA col
    const int g    = lane >> 4;                 // lane group

    // ---- band invalid mask: rows i=0..95 <-> key t = s0-16+i ----
    if (w < 2) {
        const int i  = w * 64 + lane;
        const int t  = s0 - 16 + i;
        const int tc = min(max(t, 0), SEQ - 1);
        const bool inval = (t < 0) || (t >= SEQ) || (seqMask[n * SEQ + tc] != 0);
        const unsigned long long bw = __ballot(inval);
        if (lane == 0) bm_lds[w] = bw;
    }

    // ---- stage K (384 tasks, row-major bf16) and V (448 tasks, packed) ----
#pragma unroll
    for (int it = 0; it < 4; ++it) {
        const int task = tid + it * 256;
        if (task < 384) {                       // K: i = 0..95, octet o = 0..3
            const int i = task >> 2, o = task & 3;
            const int t  = s0 - 16 + i;
            const int tc = min(max(t, 0), SEQ - 1);
            const float4 f0 = *(const float4*)&K[base_hn + tc * 32 + 8 * o];
            const float4 f1 = *(const float4*)&K[base_hn + tc * 32 + 8 * o + 4];
            BF8 u;
            u.h[0] = __float22bfloat162_rn(make_float2(f0.x, f0.y));
            u.h[1] = __float22bfloat162_rn(make_float2(f0.z, f0.w));
            u.h[2] = __float22bfloat162_rn(make_float2(f1.x, f1.y));
            u.h[3] = __float22bfloat162_rn(make_float2(f1.z, f1.w));
            *(s16x8*)&K_s[i * 32 + 8 * o] = u.v;
        } else if (task < 384 + 448) {          // V: i = 0..111, quad o = 0..3
            const int vt = task - 384;
            const int i = vt >> 2, o = vt & 3;
            const int t  = s0 - 16 + i;
            const int tc = min(max(t, 0), SEQ - 1);
            const float4 f0 = *(const float4*)&V[base_hn + tc * 32 + 4 * o];       // ch c..c+3
            const float4 f1 = *(const float4*)&V[base_hn + tc * 32 + 16 + 4 * o];  // ch c+16..
            U32 w0, w1, w2, w3;
            w0.h = __float22bfloat162_rn(make_float2(f0.x, f1.x));  // (lo=V[c], hi=V[c+16])
            w1.h = __float22bfloat162_rn(make_float2(f0.y, f1.y));
            w2.h = __float22bfloat162_rn(make_float2(f0.z, f1.z));
            w3.h = __float22bfloat162_rn(make_float2(f0.w, f1.w));
            uint4 pk4 = make_uint4(w0.u, w1.u, w2.u, w3.u);
            *(uint4*)&V_s[i * VSTR + 4 * o] = pk4;                  // 16B aligned
        }
    }

    // ---- Q B-fragment: lane holds Q[sw+q][ch 8g..8g+7], scaled, bf16 ----
    const int sw   = s0 + 16 * w;
    const int rowq = hn * SEQ + sw + q;
    const float sc = 0.17677669529663687f * 1.4426950408889634f; // 1/sqrt(32)*log2e
    const float4 q0 = *(const float4*)&Q[rowq * 32 + 8 * g];
    const float4 q1 = *(const float4*)&Q[rowq * 32 + 8 * g + 4];
    BF8 bq;
    bq.h[0] = __float22bfloat162_rn(make_float2(q0.x * sc, q0.y * sc));
    bq.h[1] = __float22bfloat162_rn(make_float2(q0.z * sc, q0.w * sc));
    bq.h[2] = __float22bfloat162_rn(make_float2(q1.x * sc, q1.y * sc));
    bq.h[3] = __float22bfloat162_rn(make_float2(q1.z * sc, q1.w * sc));

    __syncthreads();

    // ---- QK^T: 3 MFMAs; S[blk][r] = S[key=16blk+4g+r][q] ----
    f32x4 S[3];
#pragma unroll
    for (int blk = 0; blk < 3; ++blk) {
        const s16x8 ak = *(const s16x8*)&K_s[(16 * w + 16 * blk + q) * 32 + 8 * g];
        S[blk] = MFMA16(ak, bq.v, (f32x4){0.f, 0.f, 0.f, 0.f}, 0, 0, 0);
    }

    // ---- fused valid mask: vm bit j = slot j valid for this lane's query ----
    const unsigned long long bm0 = bm_lds[0], bm1 = bm_lds[1];
    const unsigned long long mI = (bm0 >> (16 * w)) | ((bm1 << (63 - 16 * w)) << 1);
    const unsigned long long vm = (((1ULL << 21) - 1) << (q + 6)) & ~mI;

    float X[3][4];
    float mx = -1e30f;
#pragma unroll
    for (int blk = 0; blk < 3; ++blk)
#pragma unroll
        for (int r = 0; r < 4; ++r) {
            const int j = 16 * blk + 4 * g + r;
            const float x = ((vm >> j) & 1ULL) ? S[blk][r] : -1e30f;
            X[blk][r] = x;
            mx = fmaxf(mx, x);
        }
    mx = fmaxf(mx, __shfl_xor(mx, 16));
    mx = fmaxf(mx, __shfl_xor(mx, 32));

    float sm = 0.f;
#pragma unroll
    for (int blk = 0; blk < 3; ++blk)
#pragma unroll
        for (int r = 0; r < 4; ++r) {
            const float e = __builtin_amdgcn_exp2f(X[blk][r] - mx);  // invalid -> 0
            X[blk][r] = e;
            sm += e;
        }
    sm += __shfl_xor(sm, 16);
    sm += __shfl_xor(sm, 32);

    // ---- pack P (unnormalized) to bf16 pairs; 1/sum deferred to epilogue ----
    unsigned pk[3][2];
#pragma unroll
    for (int blk = 0; blk < 3; ++blk) {
        U32 a, b2;
        a.h  = __float22bfloat162_rn(make_float2(X[blk][0], X[blk][1]));
        b2.h = __float22bfloat162_rn(make_float2(X[blk][2], X[blk][3]));
        pk[blk][0] = a.u;
        pk[blk][1] = b2.u;
    }

    // ---- PV (swapped): O^T = A(V) * B(P); slot j -> key 32sb + f(g,j) ----
    f32x4 O0 = {0.f, 0.f, 0.f, 0.f}, O1 = {0.f, 0.f, 0.f, 0.f};
#pragma unroll
    for (int sb = 0; sb < 2; ++sb) {
        const int R = 16 * w + 32 * sb;
        unsigned r0[4], r1[4];
#pragma unroll
        for (int jj = 0; jj < 4; ++jj) {
            r0[jj] = V_s[(R + 4 * g + jj) * VSTR + q];        // keys f(g,jj)
            r1[jj] = V_s[(R + 16 + 4 * g + jj) * VSTR + q];   // keys f(g,4+jj)
        }
        U4 A0, A1v;   // A0 = ch q-tile (low halves), A1v = ch q+16 tile (high)
        A0.u[0]  = __builtin_amdgcn_perm(r0[1], r0[0], 0x05040100u);
        A0.u[1]  = __builtin_amdgcn_perm(r0[3], r0[2], 0x05040100u);
        A0.u[2]  = __builtin_amdgcn_perm(r1[1], r1[0], 0x05040100u);
        A0.u[3]  = __builtin_amdgcn_perm(r1[3], r1[2], 0x05040100u);
        A1v.u[0] = __builtin_amdgcn_perm(r0[1], r0[0], 0x07060302u);
        A1v.u[1] = __builtin_amdgcn_perm(r0[3], r0[2], 0x07060302u);
        A1v.u[2] = __builtin_amdgcn_perm(r1[1], r1[0], 0x07060302u);
        A1v.u[3] = __builtin_amdgcn_perm(r1[3], r1[2], 0x07060302u);
        U4 Bp;
        if (sb == 0) { Bp.u[0] = pk[0][0]; Bp.u[1] = pk[0][1];
                       Bp.u[2] = pk[1][0]; Bp.u[3] = pk[1][1]; }
        else         { Bp.u[0] = pk[2][0]; Bp.u[1] = pk[2][1];
                       Bp.u[2] = 0u;       Bp.u[3] = 0u; }
        O0 = MFMA16(A0.v,  Bp.v, O0, 0, 0, 0);
        O1 = MFMA16(A1v.v, Bp.v, O1, 0, 0, 0);
    }

    // ---- epilogue: lane(q,g) owns query sw+q, ch {4g..4g+3} u {16+4g..} ----
    const float invq = 1.0f / sm;
    const int orow = sw + q;
    const float4 g0 = *(const float4*)&G[(hn * SEQ + orow) * 32 + 4 * g];
    const float4 g1 = *(const float4*)&G[(hn * SEQ + orow) * 32 + 16 + 4 * g];
    float4 o0, o1;
    o0.x = O0[0] * invq * g0.x;  o0.y = O0[1] * invq * g0.y;
    o0.z = O0[2] * invq * g0.z;  o0.w = O0[3] * invq * g0.w;
    o1.x = O1[0] * invq * g1.x;  o1.y = O1[1] * invq * g1.y;
    o1.z = O1[2] * invq * g1.z;  o1.w = O1[3] * invq * g1.w;
    float* obase = &out[((n * SEQ + orow) * HEADS + h) * 32];
    *(float4*)&obase[4 * g]      = o0;
    *(float4*)&obase[16 + 4 * g] = o1;
}

extern "C" void kernel_launch(void* const* d_in, const int* in_sizes, int n_in,
                              void* d_out, int out_size, void* d_ws, size_t ws_size,
                              hipStream_t stream) {
    const float* Q = (const float*)d_in[0];
    const float* K = (const float*)d_in[1];
    const float* V = (const float*)d_in[2];
    const float* G = (const float*)d_in[3];
    const unsigned char* seqMask = (const unsigned char*)d_in[4];
    float* out = (float*)d_out;

    const int blocks = HEADS * BATCH * (SEQ / RPB);   // 1024
    lwin_attn_kernel<<<blocks, 256, 0, stream>>>(Q, K, V, G, seqMask, out);
}